// Round 1
// baseline (293.129 us; speedup 1.0000x reference)
//
#include <hip/hip_runtime.h>

typedef __bf16 bf16_8 __attribute__((ext_vector_type(8)));
typedef float  f32x4  __attribute__((ext_vector_type(4)));
typedef float  f32x3  __attribute__((ext_vector_type(3), aligned(4)));

#define INV_SQRT3f 0.57735026918962576f

// R5: attack the real bottleneck — occupancy. R4 held 192 acc-regs/lane
// (accA+accB+accC for 2 strips) + 128 VGPR = ~320 unified regs -> 1 wave/SIMD
// (Occupancy 15.4%), so every latency was exposed (MfmaUtil 3%, HBM 25%).
//
// Changes:
//  * 1 strip (16 rows) per wave; fold accB (p2) into accC by scaling the
//    A-fragment with the lane's own v2[k]:  outv[w,k] = MFMA(v2k*s1, W01)
//    + MFMA(s2*v1k, W10). Acc = 8*4 + 3*4*4 = 80 f32/lane (= output size).
//    __launch_bounds__(256,2) -> <=256 regs -> 2 waves/SIMD guaranteed.
//  * No LDS, no __syncthreads, no per-block weight conversion: a tiny
//    converter kernel pre-transposes all weights to bf16 fragment chunks in
//    d_ws (73728 B); main kernel reads B-fragments as 16B bf16_8 global
//    loads (L1/L2-hot; ~450 MB aggregate L2 traffic ~= 13 us, not binding).
//  * outv epilogue: single dwordx3 store per (nt,r) -> contiguous 192B per
//    quarter-wave instead of 3 stride-12 scalar stores; no din2 reload.
//
// ws layout (bf16 elems): w00 [c=128][q=16][8] @0 ; w01 [c=64][q=16][8] @16384
//                         w11 [c=128][q=8][8] @24576 ; w10 [c=64][q=8][8] @32768
// chunk (c,q) element j = W[(q*8+j)*ncols + c]  (B[k][n] layout, k=q*8+j, n=c)
//
// MFMA 16x16x32 bf16 layouts (HW-verified per guide):
//   A: A[m = lane&15][k = (lane>>4)*8 + j], j=0..7
//   B: B[k = (lane>>4)*8 + j][n = lane&15]
//   C/D: D[row = (lane>>4)*4 + r][col = lane&15], r = reg 0..3

__global__ void tp_convert_weights(
    const float* __restrict__ W00, const float* __restrict__ W01,
    const float* __restrict__ W10, const float* __restrict__ W11,
    __bf16* __restrict__ ws)
{
    const int chunk = blockIdx.x * blockDim.x + threadIdx.x;
    bf16_8 v;
    if (chunk < 2048) {                       // W00: 128 cols x K=128
        const int c = chunk >> 4, q = chunk & 15;
#pragma unroll
        for (int j = 0; j < 8; ++j) v[j] = (__bf16)W00[(q * 8 + j) * 128 + c];
        *(bf16_8*)(ws + chunk * 8) = v;
    } else if (chunk < 3072) {                // W01: 64 cols x K=128
        const int idx = chunk - 2048;
        const int c = idx >> 4, q = idx & 15;
#pragma unroll
        for (int j = 0; j < 8; ++j) v[j] = (__bf16)W01[(q * 8 + j) * 64 + c];
        *(bf16_8*)(ws + 16384 + idx * 8) = v;
    } else if (chunk < 4096) {                // W11: 128 cols x K=64
        const int idx = chunk - 3072;
        const int c = idx >> 3, q = idx & 7;
#pragma unroll
        for (int j = 0; j < 8; ++j) v[j] = (__bf16)W11[(q * 8 + j) * 128 + c];
        *(bf16_8*)(ws + 24576 + idx * 8) = v;
    } else if (chunk < 4608) {                // W10: 64 cols x K=64
        const int idx = chunk - 4096;
        const int c = idx >> 3, q = idx & 7;
#pragma unroll
        for (int j = 0; j < 8; ++j) v[j] = (__bf16)W10[(q * 8 + j) * 64 + c];
        *(bf16_8*)(ws + 32768 + idx * 8) = v;
    }
}

__global__ __launch_bounds__(256, 2) void tp_main_kernel(
    const float* __restrict__ din1, const float* __restrict__ din2,
    const __bf16* __restrict__ wsw, const float* __restrict__ bias,
    float* __restrict__ out, int N, int nstrips)
{
    const int tid  = threadIdx.x;
    const int wid  = (blockIdx.x << 2) + (tid >> 6);
    if (wid >= nstrips) return;

    const int lane = tid & 63;
    const int mh   = lane & 15;   // A row within strip / D col within tile
    const int kq   = lane >> 4;   // quad

    int row = wid * 16 + mh;  if (row >= N) row = N - 1;
    const float* __restrict__ r1 = din1 + row * 320;
    const f32x4 d2 = *(const f32x4*)(din2 + row * 4);
    const float s2 = d2.x;

    const __bf16* __restrict__ w00 = wsw;
    const __bf16* __restrict__ w01 = wsw + 16384;
    const __bf16* __restrict__ w11 = wsw + 24576;
    const __bf16* __restrict__ w10 = wsw + 32768;

    f32x4 accA[8];      // out0: 128 cols
    f32x4 accV[3][4];   // outv: 64 w-cols x 3 vector comps
#pragma unroll
    for (int i = 0; i < 8; ++i) accA[i] = (f32x4)0.0f;
#pragma unroll
    for (int k = 0; k < 3; ++k)
#pragma unroll
        for (int i = 0; i < 4; ++i) accV[k][i] = (f32x4)0.0f;

    // ---- phase 1: s1 part (W00 -> accA K-steps 0..3; W01 -> accV) ----
#pragma unroll
    for (int s = 0; s < 4; ++s) {
        const int off = 32 * s + 8 * kq;
        f32x4 x0 = *(const f32x4*)(r1 + off);
        f32x4 x1 = *(const f32x4*)(r1 + off + 4);
        float xx[8] = {x0.x, x0.y, x0.z, x0.w, x1.x, x1.y, x1.z, x1.w};
        bf16_8 as2, av0, av1, av2;
#pragma unroll
        for (int j = 0; j < 8; ++j) {
            as2[j] = (__bf16)(s2   * xx[j]);
            av0[j] = (__bf16)(d2.y * xx[j]);
            av1[j] = (__bf16)(d2.z * xx[j]);
            av2[j] = (__bf16)(d2.w * xx[j]);
        }
        const int q = 4 * s + kq;
#pragma unroll
        for (int nt = 0; nt < 8; ++nt) {
            const int c = nt * 16 + mh;
            bf16_8 b = *(const bf16_8*)(w00 + (c * 16 + q) * 8);
            accA[nt] = __builtin_amdgcn_mfma_f32_16x16x32_bf16(as2, b, accA[nt], 0, 0, 0);
        }
#pragma unroll
        for (int nt = 0; nt < 4; ++nt) {
            const int c = nt * 16 + mh;
            bf16_8 b = *(const bf16_8*)(w01 + (c * 16 + q) * 8);
            accV[0][nt] = __builtin_amdgcn_mfma_f32_16x16x32_bf16(av0, b, accV[0][nt], 0, 0, 0);
            accV[1][nt] = __builtin_amdgcn_mfma_f32_16x16x32_bf16(av1, b, accV[1][nt], 0, 0, 0);
            accV[2][nt] = __builtin_amdgcn_mfma_f32_16x16x32_bf16(av2, b, accV[2][nt], 0, 0, 0);
        }
    }

    // ---- phase 2: v part (W11 -> accA K-steps 4..5; W10 -> accV) ----
#pragma unroll
    for (int s = 0; s < 2; ++s) {
        const int voff = 128 + 96 * s + 24 * kq;
        float b24[24];
#pragma unroll
        for (int qq = 0; qq < 6; ++qq) {
            f32x4 t4 = *(const f32x4*)(r1 + voff + 4 * qq);
            b24[4 * qq]     = t4.x; b24[4 * qq + 1] = t4.y;
            b24[4 * qq + 2] = t4.z; b24[4 * qq + 3] = t4.w;
        }
        bf16_8 at, ac0, ac1, ac2;
#pragma unroll
        for (int j = 0; j < 8; ++j) {
            const float e0 = b24[3 * j], e1 = b24[3 * j + 1], e2 = b24[3 * j + 2];
            at[j]  = (__bf16)(INV_SQRT3f * (e0 * d2.y + e1 * d2.z + e2 * d2.w));
            ac0[j] = (__bf16)(s2 * e0);
            ac1[j] = (__bf16)(s2 * e1);
            ac2[j] = (__bf16)(s2 * e2);
        }
        const int q = 4 * s + kq;   // K=64 chunk index 0..7
#pragma unroll
        for (int nt = 0; nt < 8; ++nt) {
            const int c = nt * 16 + mh;
            bf16_8 b = *(const bf16_8*)(w11 + (c * 8 + q) * 8);
            accA[nt] = __builtin_amdgcn_mfma_f32_16x16x32_bf16(at, b, accA[nt], 0, 0, 0);
        }
#pragma unroll
        for (int nt = 0; nt < 4; ++nt) {
            const int c = nt * 16 + mh;
            bf16_8 b = *(const bf16_8*)(w10 + (c * 8 + q) * 8);
            accV[0][nt] = __builtin_amdgcn_mfma_f32_16x16x32_bf16(ac0, b, accV[0][nt], 0, 0, 0);
            accV[1][nt] = __builtin_amdgcn_mfma_f32_16x16x32_bf16(ac1, b, accV[1][nt], 0, 0, 0);
            accV[2][nt] = __builtin_amdgcn_mfma_f32_16x16x32_bf16(ac2, b, accV[2][nt], 0, 0, 0);
        }
    }

    // ---- epilogue ----
    const int rowg0 = wid * 16 + 4 * kq;   // D row = 4*kq + r
#pragma unroll
    for (int nt = 0; nt < 8; ++nt) {
        const float bi = bias[nt * 16 + mh];
#pragma unroll
        for (int r = 0; r < 4; ++r) {
            const int rowg = rowg0 + r;
            if (rowg < N) out[rowg * 320 + nt * 16 + mh] = accA[nt][r] + bi;
        }
    }
#pragma unroll
    for (int r = 0; r < 4; ++r) {
        const int rowg = rowg0 + r;
        if (rowg < N) {
#pragma unroll
            for (int nt = 0; nt < 4; ++nt) {
                const int w = nt * 16 + mh;
                f32x3 o;
                o.x = accV[0][nt][r];
                o.y = accV[1][nt][r];
                o.z = accV[2][nt][r];
                *(f32x3*)(out + rowg * 320 + 128 + 3 * w) = o;
            }
        }
    }
}

extern "C" void kernel_launch(void* const* d_in, const int* in_sizes, int n_in,
                              void* d_out, int out_size, void* d_ws, size_t ws_size,
                              hipStream_t stream)
{
    const float* din1 = (const float*)d_in[0];
    const float* din2 = (const float*)d_in[1];
    const float* W00  = (const float*)d_in[2];
    const float* W01  = (const float*)d_in[3];
    const float* W10  = (const float*)d_in[4];
    const float* W11  = (const float*)d_in[5];
    const float* bias = (const float*)d_in[6];
    float* outp = (float*)d_out;
    __bf16* ws = (__bf16*)d_ws;

    const int N = in_sizes[0] / 320;
    const int nstrips = (N + 15) / 16;          // 16 rows per wave
    const int nblocks = (nstrips + 3) / 4;      // 4 waves per 256-thread block

    // 4608 weight chunks, one bf16_8 per thread
    hipLaunchKernelGGL(tp_convert_weights, dim3(18), dim3(256), 0, stream,
                       W00, W01, W10, W11, ws);
    hipLaunchKernelGGL(tp_main_kernel, dim3(nblocks), dim3(256), 0, stream,
                       din1, din2, ws, bias, outp, N, nstrips);
}

// Round 2
// 283.186 us; speedup vs baseline: 1.0351x; 1.0351x over previous
//
#include <hip/hip_runtime.h>

typedef __bf16 bf16_8 __attribute__((ext_vector_type(8)));
typedef float  f32x4  __attribute__((ext_vector_type(4)));
typedef float  f32x3  __attribute__((ext_vector_type(3), aligned(4)));

#define INV_SQRT3f 0.57735026918962576f

// R6: R5 post-mortem showed the regression came from moving B-fragments
// LDS -> global (longer latency, 2x traffic, 1 MFMA per load) — NOT from
// occupancy, which was never register-limited (VGPR=96). R4's real taxes
// were the per-block scalar convert/transpose (2.4M conflict cycles on
// strided u16 LDS writes) and 320 live regs.
//
// R6 combines the fixes:
//  * converter kernel writes bf16 fragments PRE-XOR-SWIZZLED into d_ws
//    (one-time, 18 blocks).
//  * main kernel: 512-thread blocks; 64KB LDS (w00/w01/w11) filled by a
//    plain 16B vector memcpy from d_ws (8 x f32x4 per thread, linear,
//    conflict-free, zero conversion ALU). One __syncthreads. w10 (8KB bf16)
//    read from global, L1-hot (8 loads/wave).
//  * 1 strip (16 rows) per wave, accB folded into accV => 80 acc f32/lane.
//    __launch_bounds__(512,4): regs <=128, LDS gives 2 blocks/CU ->
//    4 waves/SIMD (vs R4's 1).
//
// ws layout (bf16): w00 swz [c=128][q^(c&15)][8] @0 ; w01 swz [64][16][8] @16384
//                   w11 swz [c=128][q^(c&7)][8] @24576 ; w10 linear [64][8][8] @32768
// chunk (c,q) element j = W[(q*8+j)*ncols + c]  (B[k][n] layout, k=q*8+j, n=c)
//
// MFMA 16x16x32 bf16 layouts (HW-verified per guide):
//   A: A[m = lane&15][k = (lane>>4)*8 + j], j=0..7
//   B: B[k = (lane>>4)*8 + j][n = lane&15]
//   C/D: D[row = (lane>>4)*4 + r][col = lane&15], r = reg 0..3

__global__ void tp_convert_weights(
    const float* __restrict__ W00, const float* __restrict__ W01,
    const float* __restrict__ W10, const float* __restrict__ W11,
    __bf16* __restrict__ ws)
{
    const int chunk = blockIdx.x * blockDim.x + threadIdx.x;
    bf16_8 v;
    if (chunk < 2048) {                       // W00: 128 cols x K=128, swizzled
        const int c = chunk >> 4, q = chunk & 15;
#pragma unroll
        for (int j = 0; j < 8; ++j) v[j] = (__bf16)W00[(q * 8 + j) * 128 + c];
        *(bf16_8*)(ws + (c * 16 + (q ^ (c & 15))) * 8) = v;
    } else if (chunk < 3072) {                // W01: 64 cols x K=128, swizzled
        const int idx = chunk - 2048;
        const int c = idx >> 4, q = idx & 15;
#pragma unroll
        for (int j = 0; j < 8; ++j) v[j] = (__bf16)W01[(q * 8 + j) * 64 + c];
        *(bf16_8*)(ws + 16384 + (c * 16 + (q ^ (c & 15))) * 8) = v;
    } else if (chunk < 4096) {                // W11: 128 cols x K=64, swizzled
        const int idx = chunk - 3072;
        const int c = idx >> 3, q = idx & 7;
#pragma unroll
        for (int j = 0; j < 8; ++j) v[j] = (__bf16)W11[(q * 8 + j) * 128 + c];
        *(bf16_8*)(ws + 24576 + (c * 8 + (q ^ (c & 7))) * 8) = v;
    } else if (chunk < 4608) {                // W10: 64 cols x K=64, linear
        const int idx = chunk - 4096;
        const int c = idx >> 3, q = idx & 7;
#pragma unroll
        for (int j = 0; j < 8; ++j) v[j] = (__bf16)W10[(q * 8 + j) * 64 + c];
        *(bf16_8*)(ws + 32768 + idx * 8) = v;
    }
}

__global__ __launch_bounds__(512, 4) void tp_main_kernel(
    const float* __restrict__ din1, const float* __restrict__ din2,
    const __bf16* __restrict__ wsw, const float* __restrict__ bias,
    float* __restrict__ out, int N, int nstrips)
{
    __shared__ __attribute__((aligned(16))) __bf16 smem[32768];  // 64 KB
    const __bf16* sw00 = smem;           // 16384 elems
    const __bf16* sw01 = smem + 16384;   //  8192 elems
    const __bf16* sw11 = smem + 24576;   //  8192 elems

    const int tid = threadIdx.x;

    // ---- LDS fill: straight 16B memcpy of pre-swizzled weights ----
    {
        f32x4* d = (f32x4*)smem;
        const f32x4* s = (const f32x4*)wsw;
#pragma unroll
        for (int i = 0; i < 8; ++i)
            d[tid + 512 * i] = s[tid + 512 * i];
    }
    __syncthreads();

    const int wid = (blockIdx.x << 3) + (tid >> 6);
    if (wid < nstrips) {
        const int lane = tid & 63;
        const int mh   = lane & 15;   // A row within strip / D col within tile
        const int kq   = lane >> 4;   // quad

        int row = wid * 16 + mh;  if (row >= N) row = N - 1;
        const float* __restrict__ r1 = din1 + row * 320;
        const f32x4 d2 = *(const f32x4*)(din2 + row * 4);
        const float s2 = d2.x;

        const __bf16* __restrict__ w10g = wsw + 32768;

        f32x4 accA[8];      // out0: 128 cols
        f32x4 accV[3][4];   // outv: 64 w-cols x 3 vector comps
#pragma unroll
        for (int i = 0; i < 8; ++i) accA[i] = (f32x4)0.0f;
#pragma unroll
        for (int k = 0; k < 3; ++k)
#pragma unroll
            for (int i = 0; i < 4; ++i) accV[k][i] = (f32x4)0.0f;

        // ---- phase 1: s1 part (W00 -> accA K-steps 0..3; W01 -> accV) ----
#pragma unroll
        for (int s = 0; s < 4; ++s) {
            const int off = 32 * s + 8 * kq;
            f32x4 x0 = *(const f32x4*)(r1 + off);
            f32x4 x1 = *(const f32x4*)(r1 + off + 4);
            float xx[8] = {x0.x, x0.y, x0.z, x0.w, x1.x, x1.y, x1.z, x1.w};
            bf16_8 as2, av0, av1, av2;
#pragma unroll
            for (int j = 0; j < 8; ++j) {
                as2[j] = (__bf16)(s2   * xx[j]);
                av0[j] = (__bf16)(d2.y * xx[j]);
                av1[j] = (__bf16)(d2.z * xx[j]);
                av2[j] = (__bf16)(d2.w * xx[j]);
            }
            const int q = 4 * s + kq;
#pragma unroll
            for (int nt = 0; nt < 8; ++nt) {
                const int c = nt * 16 + mh;
                bf16_8 b = *(const bf16_8*)(sw00 + (c * 16 + (q ^ mh)) * 8);
                accA[nt] = __builtin_amdgcn_mfma_f32_16x16x32_bf16(as2, b, accA[nt], 0, 0, 0);
            }
#pragma unroll
            for (int nt = 0; nt < 4; ++nt) {
                const int c = nt * 16 + mh;
                bf16_8 b = *(const bf16_8*)(sw01 + (c * 16 + (q ^ mh)) * 8);
                accV[0][nt] = __builtin_amdgcn_mfma_f32_16x16x32_bf16(av0, b, accV[0][nt], 0, 0, 0);
                accV[1][nt] = __builtin_amdgcn_mfma_f32_16x16x32_bf16(av1, b, accV[1][nt], 0, 0, 0);
                accV[2][nt] = __builtin_amdgcn_mfma_f32_16x16x32_bf16(av2, b, accV[2][nt], 0, 0, 0);
            }
        }

        // ---- phase 2: v part (W11 -> accA K-steps 4..5; W10 -> accV) ----
#pragma unroll
        for (int s = 0; s < 2; ++s) {
            const int voff = 128 + 96 * s + 24 * kq;
            float b24[24];
#pragma unroll
            for (int qq = 0; qq < 6; ++qq) {
                f32x4 t4 = *(const f32x4*)(r1 + voff + 4 * qq);
                b24[4 * qq]     = t4.x; b24[4 * qq + 1] = t4.y;
                b24[4 * qq + 2] = t4.z; b24[4 * qq + 3] = t4.w;
            }
            bf16_8 at, ac0, ac1, ac2;
#pragma unroll
            for (int j = 0; j < 8; ++j) {
                const float e0 = b24[3 * j], e1 = b24[3 * j + 1], e2 = b24[3 * j + 2];
                at[j]  = (__bf16)(INV_SQRT3f * (e0 * d2.y + e1 * d2.z + e2 * d2.w));
                ac0[j] = (__bf16)(s2 * e0);
                ac1[j] = (__bf16)(s2 * e1);
                ac2[j] = (__bf16)(s2 * e2);
            }
            const int q = 4 * s + kq;   // K=64 chunk index 0..7
#pragma unroll
            for (int nt = 0; nt < 8; ++nt) {
                const int c = nt * 16 + mh;
                bf16_8 b = *(const bf16_8*)(sw11 + (c * 8 + (q ^ (mh & 7))) * 8);
                accA[nt] = __builtin_amdgcn_mfma_f32_16x16x32_bf16(at, b, accA[nt], 0, 0, 0);
            }
#pragma unroll
            for (int nt = 0; nt < 4; ++nt) {
                const int c = nt * 16 + mh;
                bf16_8 b = *(const bf16_8*)(w10g + (c * 8 + q) * 8);
                accV[0][nt] = __builtin_amdgcn_mfma_f32_16x16x32_bf16(ac0, b, accV[0][nt], 0, 0, 0);
                accV[1][nt] = __builtin_amdgcn_mfma_f32_16x16x32_bf16(ac1, b, accV[1][nt], 0, 0, 0);
                accV[2][nt] = __builtin_amdgcn_mfma_f32_16x16x32_bf16(ac2, b, accV[2][nt], 0, 0, 0);
            }
        }

        // ---- epilogue ----
        const int rowg0 = wid * 16 + 4 * kq;   // D row = 4*kq + r
#pragma unroll
        for (int nt = 0; nt < 8; ++nt) {
            const float bi = bias[nt * 16 + mh];
#pragma unroll
            for (int r = 0; r < 4; ++r) {
                const int rowg = rowg0 + r;
                if (rowg < N) out[rowg * 320 + nt * 16 + mh] = accA[nt][r] + bi;
            }
        }
#pragma unroll
        for (int r = 0; r < 4; ++r) {
            const int rowg = rowg0 + r;
            if (rowg < N) {
#pragma unroll
                for (int nt = 0; nt < 4; ++nt) {
                    const int w = nt * 16 + mh;
                    f32x3 o;
                    o.x = accV[0][nt][r];
                    o.y = accV[1][nt][r];
                    o.z = accV[2][nt][r];
                    *(f32x3*)(out + rowg * 320 + 128 + 3 * w) = o;
                }
            }
        }
    }
}

extern "C" void kernel_launch(void* const* d_in, const int* in_sizes, int n_in,
                              void* d_out, int out_size, void* d_ws, size_t ws_size,
                              hipStream_t stream)
{
    const float* din1 = (const float*)d_in[0];
    const float* din2 = (const float*)d_in[1];
    const float* W00  = (const float*)d_in[2];
    const float* W01  = (const float*)d_in[3];
    const float* W10  = (const float*)d_in[4];
    const float* W11  = (const float*)d_in[5];
    const float* bias = (const float*)d_in[6];
    float* outp = (float*)d_out;
    __bf16* ws = (__bf16*)d_ws;

    const int N = in_sizes[0] / 320;
    const int nstrips = (N + 15) / 16;          // 16 rows per wave
    const int nblocks = (nstrips + 7) / 8;      // 8 waves per 512-thread block

    // 4608 weight chunks, one bf16_8 per thread
    hipLaunchKernelGGL(tp_convert_weights, dim3(18), dim3(256), 0, stream,
                       W00, W01, W10, W11, ws);
    hipLaunchKernelGGL(tp_main_kernel, dim3(nblocks), dim3(512), 0, stream,
                       din1, din2, ws, bias, outp, N, nstrips);
}

// Round 3
// 264.331 us; speedup vs baseline: 1.1089x; 1.0713x over previous
//
#include <hip/hip_runtime.h>

typedef __bf16 bf16_8 __attribute__((ext_vector_type(8)));
typedef float  f32x4  __attribute__((ext_vector_type(4)));
typedef float  f32x3  __attribute__((ext_vector_type(3), aligned(4)));

#define INV_SQRT3f 0.57735026918962576f

// R7: R6 post-mortem — __launch_bounds__(512,4) forced VGPR_Count=64, which
// killed ILP: the 20 f32x4 din1 loads per lane couldn't be kept in flight,
// so each s-step ate a full HBM/L2 round trip (kernel 114us vs ~49us HBM
// floor, all pipes <35%). R4 had ILP but 1 wave/SIMD; R6 had 2.5 waves but
// no ILP. R7 takes both:
//  * __launch_bounds__(512,2): ~200 regs budget -> 2 waves/SIMD.
//  * Explicit register prefetch of ALL din1 (20 x f32x4 = 80 regs) + din2
//    BEFORE the barrier. Order: LDS-fill loads first, din1 burst second,
//    ds_writes third (their vmcnt wait only covers the fill loads), so the
//    din1 latency hides under the fill+barrier and co-resident wave compute.
//  * Post-barrier compute touches only registers + LDS (+8 L1-hot w10
//    fragment loads). Everything else identical to R6.
//
// ws layout (bf16): w00 swz [c=128][q^(c&15)][8] @0 ; w01 swz [64][16][8] @16384
//                   w11 swz [c=128][q^(c&7)][8] @24576 ; w10 linear [64][8][8] @32768
// chunk (c,q) element j = W[(q*8+j)*ncols + c]  (B[k][n] layout, k=q*8+j, n=c)
//
// MFMA 16x16x32 bf16 layouts (HW-verified per guide):
//   A: A[m = lane&15][k = (lane>>4)*8 + j], j=0..7
//   B: B[k = (lane>>4)*8 + j][n = lane&15]
//   C/D: D[row = (lane>>4)*4 + r][col = lane&15], r = reg 0..3

__global__ void tp_convert_weights(
    const float* __restrict__ W00, const float* __restrict__ W01,
    const float* __restrict__ W10, const float* __restrict__ W11,
    __bf16* __restrict__ ws)
{
    const int chunk = blockIdx.x * blockDim.x + threadIdx.x;
    bf16_8 v;
    if (chunk < 2048) {                       // W00: 128 cols x K=128, swizzled
        const int c = chunk >> 4, q = chunk & 15;
#pragma unroll
        for (int j = 0; j < 8; ++j) v[j] = (__bf16)W00[(q * 8 + j) * 128 + c];
        *(bf16_8*)(ws + (c * 16 + (q ^ (c & 15))) * 8) = v;
    } else if (chunk < 3072) {                // W01: 64 cols x K=128, swizzled
        const int idx = chunk - 2048;
        const int c = idx >> 4, q = idx & 15;
#pragma unroll
        for (int j = 0; j < 8; ++j) v[j] = (__bf16)W01[(q * 8 + j) * 64 + c];
        *(bf16_8*)(ws + 16384 + (c * 16 + (q ^ (c & 15))) * 8) = v;
    } else if (chunk < 4096) {                // W11: 128 cols x K=64, swizzled
        const int idx = chunk - 3072;
        const int c = idx >> 3, q = idx & 7;
#pragma unroll
        for (int j = 0; j < 8; ++j) v[j] = (__bf16)W11[(q * 8 + j) * 128 + c];
        *(bf16_8*)(ws + 24576 + (c * 8 + (q ^ (c & 7))) * 8) = v;
    } else if (chunk < 4608) {                // W10: 64 cols x K=64, linear
        const int idx = chunk - 4096;
        const int c = idx >> 3, q = idx & 7;
#pragma unroll
        for (int j = 0; j < 8; ++j) v[j] = (__bf16)W10[(q * 8 + j) * 64 + c];
        *(bf16_8*)(ws + 32768 + idx * 8) = v;
    }
}

__global__ __launch_bounds__(512, 2) void tp_main_kernel(
    const float* __restrict__ din1, const float* __restrict__ din2,
    const __bf16* __restrict__ wsw, const float* __restrict__ bias,
    float* __restrict__ out, int N, int nstrips)
{
    __shared__ __attribute__((aligned(16))) __bf16 smem[32768];  // 64 KB
    const __bf16* sw00 = smem;           // 16384 elems
    const __bf16* sw01 = smem + 16384;   //  8192 elems
    const __bf16* sw11 = smem + 24576;   //  8192 elems

    const int tid  = threadIdx.x;
    const int wid  = (blockIdx.x << 3) + (tid >> 6);
    const int lane = tid & 63;
    const int mh   = lane & 15;   // A row within strip / D col within tile
    const int kq   = lane >> 4;   // quad

    // clamped strip for tail waves (they prefetch harmlessly, skip compute)
    const int swid = wid < nstrips ? wid : nstrips - 1;
    int row = swid * 16 + mh;  if (row >= N) row = N - 1;
    const float* __restrict__ r1 = din1 + row * 320;

    // ---- 1) LDS-fill loads (barrier-critical, issue first) ----
    f32x4 fill[8];
    {
        const f32x4* s = (const f32x4*)wsw;
#pragma unroll
        for (int i = 0; i < 8; ++i) fill[i] = s[tid + 512 * i];
    }

    // ---- 2) din1/din2 register prefetch burst (hides under fill+barrier) ----
    f32x4 p1[8];    // phase-1 data: s=0..3, 8 floats each
#pragma unroll
    for (int s = 0; s < 4; ++s) {
        p1[2 * s]     = *(const f32x4*)(r1 + 32 * s + 8 * kq);
        p1[2 * s + 1] = *(const f32x4*)(r1 + 32 * s + 8 * kq + 4);
    }
    f32x4 p2[12];   // phase-2 data: s=0..1, 24 floats each
#pragma unroll
    for (int s = 0; s < 2; ++s)
#pragma unroll
        for (int qq = 0; qq < 6; ++qq)
            p2[6 * s + qq] = *(const f32x4*)(r1 + 128 + 96 * s + 24 * kq + 4 * qq);
    const f32x4 d2 = *(const f32x4*)(din2 + row * 4);
    const float s2 = d2.x;

    // ---- 3) LDS writes (wait only on fill loads) + barrier ----
    {
        f32x4* d = (f32x4*)smem;
#pragma unroll
        for (int i = 0; i < 8; ++i) d[tid + 512 * i] = fill[i];
    }
    __syncthreads();

    if (wid < nstrips) {
        const __bf16* __restrict__ w10g = wsw + 32768;

        f32x4 accA[8];      // out0: 128 cols
        f32x4 accV[3][4];   // outv: 64 w-cols x 3 vector comps
#pragma unroll
        for (int i = 0; i < 8; ++i) accA[i] = (f32x4)0.0f;
#pragma unroll
        for (int k = 0; k < 3; ++k)
#pragma unroll
            for (int i = 0; i < 4; ++i) accV[k][i] = (f32x4)0.0f;

        // ---- phase 1: s1 part (W00 -> accA K-steps 0..3; W01 -> accV) ----
#pragma unroll
        for (int s = 0; s < 4; ++s) {
            const f32x4 x0 = p1[2 * s];
            const f32x4 x1 = p1[2 * s + 1];
            float xx[8] = {x0.x, x0.y, x0.z, x0.w, x1.x, x1.y, x1.z, x1.w};
            bf16_8 as2, av0, av1, av2;
#pragma unroll
            for (int j = 0; j < 8; ++j) {
                as2[j] = (__bf16)(s2   * xx[j]);
                av0[j] = (__bf16)(d2.y * xx[j]);
                av1[j] = (__bf16)(d2.z * xx[j]);
                av2[j] = (__bf16)(d2.w * xx[j]);
            }
            const int q = 4 * s + kq;
#pragma unroll
            for (int nt = 0; nt < 8; ++nt) {
                const int c = nt * 16 + mh;
                bf16_8 b = *(const bf16_8*)(sw00 + (c * 16 + (q ^ mh)) * 8);
                accA[nt] = __builtin_amdgcn_mfma_f32_16x16x32_bf16(as2, b, accA[nt], 0, 0, 0);
            }
#pragma unroll
            for (int nt = 0; nt < 4; ++nt) {
                const int c = nt * 16 + mh;
                bf16_8 b = *(const bf16_8*)(sw01 + (c * 16 + (q ^ mh)) * 8);
                accV[0][nt] = __builtin_amdgcn_mfma_f32_16x16x32_bf16(av0, b, accV[0][nt], 0, 0, 0);
                accV[1][nt] = __builtin_amdgcn_mfma_f32_16x16x32_bf16(av1, b, accV[1][nt], 0, 0, 0);
                accV[2][nt] = __builtin_amdgcn_mfma_f32_16x16x32_bf16(av2, b, accV[2][nt], 0, 0, 0);
            }
        }

        // ---- phase 2: v part (W11 -> accA K-steps 4..5; W10 -> accV) ----
#pragma unroll
        for (int s = 0; s < 2; ++s) {
            float b24[24];
#pragma unroll
            for (int qq = 0; qq < 6; ++qq) {
                const f32x4 t4 = p2[6 * s + qq];
                b24[4 * qq]     = t4.x; b24[4 * qq + 1] = t4.y;
                b24[4 * qq + 2] = t4.z; b24[4 * qq + 3] = t4.w;
            }
            bf16_8 at, ac0, ac1, ac2;
#pragma unroll
            for (int j = 0; j < 8; ++j) {
                const float e0 = b24[3 * j], e1 = b24[3 * j + 1], e2 = b24[3 * j + 2];
                at[j]  = (__bf16)(INV_SQRT3f * (e0 * d2.y + e1 * d2.z + e2 * d2.w));
                ac0[j] = (__bf16)(s2 * e0);
                ac1[j] = (__bf16)(s2 * e1);
                ac2[j] = (__bf16)(s2 * e2);
            }
            const int q = 4 * s + kq;   // K=64 chunk index 0..7
#pragma unroll
            for (int nt = 0; nt < 8; ++nt) {
                const int c = nt * 16 + mh;
                bf16_8 b = *(const bf16_8*)(sw11 + (c * 8 + (q ^ (mh & 7))) * 8);
                accA[nt] = __builtin_amdgcn_mfma_f32_16x16x32_bf16(at, b, accA[nt], 0, 0, 0);
            }
#pragma unroll
            for (int nt = 0; nt < 4; ++nt) {
                const int c = nt * 16 + mh;
                bf16_8 b = *(const bf16_8*)(w10g + (c * 8 + q) * 8);
                accV[0][nt] = __builtin_amdgcn_mfma_f32_16x16x32_bf16(ac0, b, accV[0][nt], 0, 0, 0);
                accV[1][nt] = __builtin_amdgcn_mfma_f32_16x16x32_bf16(ac1, b, accV[1][nt], 0, 0, 0);
                accV[2][nt] = __builtin_amdgcn_mfma_f32_16x16x32_bf16(ac2, b, accV[2][nt], 0, 0, 0);
            }
        }

        // ---- epilogue ----
        const int rowg0 = wid * 16 + 4 * kq;   // D row = 4*kq + r
#pragma unroll
        for (int nt = 0; nt < 8; ++nt) {
            const float bi = bias[nt * 16 + mh];
#pragma unroll
            for (int r = 0; r < 4; ++r) {
                const int rowg = rowg0 + r;
                if (rowg < N) out[rowg * 320 + nt * 16 + mh] = accA[nt][r] + bi;
            }
        }
#pragma unroll
        for (int r = 0; r < 4; ++r) {
            const int rowg = rowg0 + r;
            if (rowg < N) {
#pragma unroll
                for (int nt = 0; nt < 4; ++nt) {
                    const int w = nt * 16 + mh;
                    f32x3 o;
                    o.x = accV[0][nt][r];
                    o.y = accV[1][nt][r];
                    o.z = accV[2][nt][r];
                    *(f32x3*)(out + rowg * 320 + 128 + 3 * w) = o;
                }
            }
        }
    }
}

extern "C" void kernel_launch(void* const* d_in, const int* in_sizes, int n_in,
                              void* d_out, int out_size, void* d_ws, size_t ws_size,
                              hipStream_t stream)
{
    const float* din1 = (const float*)d_in[0];
    const float* din2 = (const float*)d_in[1];
    const float* W00  = (const float*)d_in[2];
    const float* W01  = (const float*)d_in[3];
    const float* W10  = (const float*)d_in[4];
    const float* W11  = (const float*)d_in[5];
    const float* bias = (const float*)d_in[6];
    float* outp = (float*)d_out;
    __bf16* ws = (__bf16*)d_ws;

    const int N = in_sizes[0] / 320;
    const int nstrips = (N + 15) / 16;          // 16 rows per wave
    const int nblocks = (nstrips + 7) / 8;      // 8 waves per 512-thread block

    // 4608 weight chunks, one bf16_8 per thread
    hipLaunchKernelGGL(tp_convert_weights, dim3(18), dim3(256), 0, stream,
                       W00, W01, W10, W11, ws);
    hipLaunchKernelGGL(tp_main_kernel, dim3(nblocks), dim3(512), 0, stream,
                       din1, din2, ws, bias, outp, N, nstrips);
}